// Round 9
// baseline (2864.874 us; speedup 1.0000x reference)
//
#include <hip/hip_runtime.h>
#include <hip/hip_bf16.h>

// Bidirectional LSTM, B=32 T=512 D=512 U=512, fp32 in/out, bf16 MFMA internals.
// Phase 1: xg = x @ [Wf||Wb] + b  (bf16 MFMA GEMM, permuted columns)
// Phase 2: persistent recurrence, R12: coalesced self-certifying records at
//          AGENT scope (__hip_atomic_* only — raw sc0 falsified in R10/R11).
//          - exchange = 8B records {u32 payload(h[b],h[b+16]), u32 step}.
//            Data IS the flag: poll load returns the payload; no flags, no
//            store-ack drains, no ordering assumptions (protocol proven
//            correct at agent scope in R6b/R8).
//          - coalesced: adjacent lanes 16B apart, 2x8B atomic loads/lane/ks ->
//            ~1KB contiguous per wave instruction pair (pattern proven in R9).
//          - per-lane selective retry; spin bound = hang insurance only.
//          - R7/R9 compute core: swapped-operand MFMA (lane-local gates),
//            chunk-XOR LDS swizzle (0 bank conflicts), ONE lgkm barrier/step,
//            xg software-pipelined one step ahead.
// Phase 3: out = fwd + bwd

typedef __attribute__((ext_vector_type(8))) __bf16 bf16x8;
typedef __attribute__((ext_vector_type(4))) __bf16 bf16x4;
typedef __attribute__((ext_vector_type(4))) float fvec4;

#define AS_G(p) ((const __attribute__((address_space(1))) void*)(p))
#define AS_L(p) ((__attribute__((address_space(3))) void*)(p))

__device__ __forceinline__ float sigm(float x) {
  return __builtin_amdgcn_rcpf(1.f + __expf(-x));
}
__device__ __forceinline__ float tanh_f(float x) {
  return 1.f - 2.f * __builtin_amdgcn_rcpf(__expf(2.f * x) + 1.f);
}

// ---------------- conversions ----------------

__global__ void k_convert_x(const float* __restrict__ x, __bf16* __restrict__ xb) {
  size_t i = ((size_t)blockIdx.x * 256 + threadIdx.x) * 8;
  fvec4 a = *(const fvec4*)(x + i);
  fvec4 b = *(const fvec4*)(x + i + 4);
  bf16x8 o;
#pragma unroll
  for (int j = 0; j < 4; ++j) { o[j] = (__bf16)a[j]; o[4 + j] = (__bf16)b[j]; }
  *(bf16x8*)(xb + i) = o;
}

// dst[p][k] = src[k][orig(p)] as bf16. Permutation: p = g*64 + w*16 + jj*4 + gate
// <-> orig = gate*512 + g*16 + w*4 + jj  (Keras gate order i,f,c,o).
__global__ void k_build_T(const float* __restrict__ src, const float* __restrict__ bvec,
                          __bf16* __restrict__ dst, float* __restrict__ bias_out) {
  int p = blockIdx.x;
  int g = p >> 6, r = p & 63, w = r >> 4, q = r & 15, jj = q >> 2, gate = q & 3;
  int orig = gate * 512 + g * 16 + w * 4 + jj;
  for (int k = threadIdx.x; k < 512; k += 256)
    dst[(size_t)p * 512 + k] = (__bf16)src[(size_t)k * 2048 + orig];
  if (bias_out && threadIdx.x == 0) bias_out[p] = bvec[orig];
}

// init records: rbuf[dir 2][par 2][ks 16][b16 16][u' 32] u64 {payload, step}.
// parity 0 = h(0)=z with step 0; parity 1 zeroed (step 0 never matches odd kt).
// Rewritten EVERY launch (graph replay safe).
__global__ void k_init_rec(const float* __restrict__ z,
                           unsigned long long* __restrict__ rbuf) {
  int idx = blockIdx.x * 256 + threadIdx.x;      // 0..32767
  int par = (idx >> 13) & 1;
  int rem = idx & 8191;
  unsigned long long v = 0ull;
  if (par == 0) {
    int ks = rem >> 9, b16 = (rem >> 5) & 15, u2 = rem & 31;
    int uu = ks * 32 + u2;
    union { __bf16 h[2]; unsigned u32; } pk;
    pk.h[0] = (__bf16)z[b16 * 512 + uu];
    pk.h[1] = (__bf16)z[(b16 + 16) * 512 + uu];
    v = (unsigned long long)pk.u32;              // step 0 in high word
  }
  rbuf[idx] = v;
}

// ---------------- input GEMM: [16384,512] x [4096,512]^T -> bf16 [16384,4096] ----------------

__global__ __launch_bounds__(256, 2) void k_gemm_xw(
    const __bf16* __restrict__ A,   // [16384][512] bf16
    const __bf16* __restrict__ Bt,  // [4096][512] bf16 (permuted W^T)
    const float* __restrict__ bias, // [4096] permuted
    __bf16* __restrict__ C)         // [16384][4096]
{
  __shared__ __align__(16) __bf16 As[128 * 32];
  __shared__ __align__(16) __bf16 Bs[128 * 32];
  const int tid = threadIdx.x;
  const int w = tid >> 6, lane = tid & 63, quad = lane >> 4, l15 = lane & 15;
  const int m0 = blockIdx.y * 128, n0 = blockIdx.x * 128;
  const int wm = w & 1, wn = w >> 1;

  fvec4 acc[4][4];
  const fvec4 zero = {0.f, 0.f, 0.f, 0.f};
#pragma unroll
  for (int i = 0; i < 4; ++i)
#pragma unroll
    for (int j = 0; j < 4; ++j) acc[i][j] = zero;

  for (int kb = 0; kb < 16; ++kb) {
    const int k0 = kb * 32;
#pragma unroll
    for (int i = 0; i < 2; ++i) {
      const int c = (i * 4 + w) * 64 + lane;      // 16B chunk id, 0..511
      const int row = c >> 2, kk = (c & 3) * 8;
      __builtin_amdgcn_global_load_lds(AS_G(A + (size_t)(m0 + row) * 512 + k0 + kk),
                                       AS_L(As + (size_t)(i * 4 + w) * 512), 16, 0, 0);
      __builtin_amdgcn_global_load_lds(AS_G(Bt + (size_t)(n0 + row) * 512 + k0 + kk),
                                       AS_L(Bs + (size_t)(i * 4 + w) * 512), 16, 0, 0);
    }
    __syncthreads();
    bf16x8 af[4], bfr[4];
#pragma unroll
    for (int mt = 0; mt < 4; ++mt)
      af[mt] = *(const bf16x8*)(As + (wm * 64 + mt * 16 + l15) * 32 + quad * 8);
#pragma unroll
    for (int nt = 0; nt < 4; ++nt)
      bfr[nt] = *(const bf16x8*)(Bs + (wn * 64 + nt * 16 + l15) * 32 + quad * 8);
#pragma unroll
    for (int mt = 0; mt < 4; ++mt)
#pragma unroll
      for (int nt = 0; nt < 4; ++nt)
        acc[mt][nt] = __builtin_amdgcn_mfma_f32_16x16x32_bf16(af[mt], bfr[nt], acc[mt][nt], 0, 0, 0);
    __syncthreads();
  }

#pragma unroll
  for (int nt = 0; nt < 4; ++nt) {
    const int col = n0 + wn * 64 + nt * 16 + l15;
    const float bv = bias[col];
#pragma unroll
    for (int mt = 0; mt < 4; ++mt) {
      const int rowb = m0 + wm * 64 + mt * 16 + quad * 4;
#pragma unroll
      for (int r = 0; r < 4; ++r)
        C[(size_t)(rowb + r) * 4096 + col] = (__bf16)(acc[mt][nt][r] + bv);
    }
  }
}

// ---------------- persistent recurrence (agent-scope, data-as-flag) ----------------
// 64 blocks: dir = blk>>5, group g = blk&31 owns units u in [g*16, g*16+16).
// Lane (w,quad,l15): unit u = g*16+w*4+quad, batches b = l15 and l15+16.
// Records rbuf[dir][par][ks][b16][u'] u64 {payload, step}; __hip_atomic AGENT.
// Per step kt: poll+stage (thread t: 2x8B atomic loads x 16 ks, lanes 16B apart
// -> coalesced; accept iff step words == kt; per-lane retry) -> LDS (XOR
// swizzle) -> ONE lgkm barrier -> MFMA (swapped, lane-local gates) -> act ->
// publish record {h, kt+1} fire-and-forget -> out stores.
// Correctness (no ordering assumptions beyond 8B single-copy atomicity):
//  - step word certifies payload (same 8B store).
//  - Lost updates: P overwrites slot R (parity p, step kt -> kt+2) at end of
//    its step kt+1, after P's poll(kt+1) saw ALL kt+1 records; any consumer C's
//    kt+1 record is published only after C's loads of step-kt records (incl. R)
//    returned and were consumed (data dep through MFMA). So R was consumed.
//  - P's own WAW on a slot (kt+1 vs kt+3): separated by poll waits in between.
//  - '== kt' exact: slot values are only init/kt-2 (stale) or kt.
// Liveness: records for kt published unconditionally at end of step kt-1 ->
// poll terminates by induction; spin bound converts any broken premise into
// wrong-data-not-hang (diagnosable).

__global__ __launch_bounds__(256, 1) void k_lstm_rec(
    const __bf16* __restrict__ xg,            // [16384][4096] permuted
    const float* __restrict__ z,              // [32][512]
    const __bf16* __restrict__ UT,            // [2][2048][512] permuted
    unsigned long long* __restrict__ rbuf,    // [2][2][8192] records
    float* __restrict__ outf,                 // d_out [32][512][512] (fwd)
    __bf16* __restrict__ outb)                // ws [32][512][512] (bwd)
{
  const int blk = blockIdx.x, dir = blk >> 5, g = blk & 31;
  const int tid = threadIdx.x, w = tid >> 6, lane = tid & 63;
  const int quad = lane >> 4, l15 = lane & 15;
  __shared__ __align__(16) char h_lds[2][16 * 2048];   // 64 KB double buffer

  // U^T slice resident in registers for all 512 steps (64 VGPRs)
  bf16x8 breg[16];
  {
    const __bf16* up = UT + ((size_t)dir * 2048 + g * 64 + w * 16 + l15) * 512 + quad * 8;
#pragma unroll
    for (int ks = 0; ks < 16; ++ks) breg[ks] = *(const bf16x8*)(up + ks * 32);
  }

  const int u = g * 16 + w * 4 + quad;
  float c0 = z[l15 * 512 + u];
  float c1 = z[(l15 + 16) * 512 + u];

  // staging mapping: thread t owns (b16 = t>>4, units 2(t&15), 2(t&15)+1);
  // record element offset (ks=0): adjacent lanes 16B apart -> coalesced.
  const int recoff = (tid >> 4) * 32 + (tid & 15) * 2;
  const int b16s = tid >> 4, upair = (tid & 15) * 2;
  const int swz_s = (b16s >> 1) & 3;
  const int off0 = b16s * 64 + (((upair >> 3) ^ swz_s) * 16) + (upair & 7) * 2;
  const int swz_f = (l15 >> 1) & 3;
  const int foff = l15 * 64 + ((quad ^ swz_f) * 16);

  unsigned long long* rb_dir = rbuf + (size_t)dir * 16384;   // [par][8192]
  // producer record index: [ks_u = g>>1][b16 = l15][u' = (g&1)*16 + w*4 + quad]
  const int pidx = (g >> 1) * 512 + l15 * 32 + (g & 1) * 16 + w * 4 + quad;
  const size_t xgoff = (size_t)dir * 2048 + g * 64 + w * 16 + quad * 4;

  // prime xg for kt=0
  const int t0 = dir ? 511 : 0;
  bf16x4 xA = *(const bf16x4*)(xg + (size_t)(l15 * 512 + t0) * 4096 + xgoff);
  bf16x4 xB = *(const bf16x4*)(xg + (size_t)((l15 + 16) * 512 + t0) * 4096 + xgoff);

  for (int kt = 0; kt < 512; ++kt) {
    const int pr = kt & 1;

    // ---- poll-on-data + staging: 32 x 8B agent loads, per-lane retry ----
    unsigned long long rec[32];
    {
      const unsigned long long* srcp = rb_dir + (size_t)pr * 8192 + recoff;
      const unsigned expect = (unsigned)kt;
      int need = 1, spin = 0;
      for (;;) {
        if (need) {
#pragma unroll
          for (int ks = 0; ks < 16; ++ks) {
            rec[2 * ks] = __hip_atomic_load(srcp + ks * 512,
                              __ATOMIC_RELAXED, __HIP_MEMORY_SCOPE_AGENT);
            rec[2 * ks + 1] = __hip_atomic_load(srcp + ks * 512 + 1,
                              __ATOMIC_RELAXED, __HIP_MEMORY_SCOPE_AGENT);
          }
          int ok = 1;
#pragma unroll
          for (int i = 0; i < 32; ++i)
            ok &= ((unsigned)(rec[i] >> 32) == expect);
          need = !ok;
        }
        if (!__ballot(need)) break;
        if (++spin > (1 << 13)) break;   // hang insurance: wrong-data beats hang
        __builtin_amdgcn_s_sleep(1);
      }
    }

    // ---- pack payloads into LDS (conflict-free swizzled b32 writes) ----
    {
      char* dst = h_lds[pr];
#pragma unroll
      for (int ks = 0; ks < 16; ++ks) {
        const unsigned d0 = (unsigned)rec[2 * ks], d1 = (unsigned)rec[2 * ks + 1];
        *(unsigned*)(dst + ks * 2048 + off0) = (d0 & 0xffffu) | (d1 << 16);
        *(unsigned*)(dst + ks * 2048 + off0 + 1024) = (d0 >> 16) | (d1 & 0xffff0000u);
      }
    }
    // the ONE barrier per step: staging visible to all waves (LDS-only drain)
    asm volatile("s_waitcnt lgkmcnt(0)\n\ts_barrier" ::: "memory");

    // issue next-step xg now (retires under MFMA+act, ahead of next poll wait)
    const int tn = dir ? (kt < 511 ? 510 - kt : 0) : (kt < 511 ? kt + 1 : 511);
    bf16x4 nxA = *(const bf16x4*)(xg + (size_t)(l15 * 512 + tn) * 4096 + xgoff);
    bf16x4 nxB = *(const bf16x4*)(xg + (size_t)((l15 + 16) * 512 + tn) * 4096 + xgoff);

    fvec4 acc0 = {0.f, 0.f, 0.f, 0.f}, acc1 = {0.f, 0.f, 0.f, 0.f};
    {
      const char* rb = h_lds[pr];
#pragma unroll 8
      for (int ks = 0; ks < 16; ++ks) {
        bf16x8 a0 = *(const bf16x8*)(rb + ks * 2048 + foff);
        bf16x8 a1 = *(const bf16x8*)(rb + ks * 2048 + 1024 + foff);
        acc0 = __builtin_amdgcn_mfma_f32_16x16x32_bf16(breg[ks], a0, acc0, 0, 0, 0);
        acc1 = __builtin_amdgcn_mfma_f32_16x16x32_bf16(breg[ks], a1, acc1, 0, 0, 0);
      }
    }

    // gates lane-local: acc[reg] = gate reg (i,f,c,o) of this lane's unit
    const int t = dir ? (511 - kt) : kt;
    float ii = sigm(acc0[0] + (float)xA[0]);
    float ff = sigm(acc0[1] + (float)xA[1]);
    float cc = tanh_f(acc0[2] + (float)xA[2]);
    float oo = sigm(acc0[3] + (float)xA[3]);
    c0 = ff * c0 + ii * cc;
    const float h0 = oo * tanh_f(c0);

    ii = sigm(acc1[0] + (float)xB[0]);
    ff = sigm(acc1[1] + (float)xB[1]);
    cc = tanh_f(acc1[2] + (float)xB[2]);
    oo = sigm(acc1[3] + (float)xB[3]);
    c1 = ff * c1 + ii * cc;
    const float h1 = oo * tanh_f(c1);

    // publish self-certifying record {payload, kt+1}: one 8B agent store,
    // fire-and-forget (no drain, no flag, no ordering requirement)
    union { __bf16 h[2]; unsigned u32; } pk;
    pk.h[0] = (__bf16)h0;
    pk.h[1] = (__bf16)h1;
    {
      const unsigned long long rv =
          (unsigned long long)pk.u32 | ((unsigned long long)(unsigned)(kt + 1) << 32);
      __hip_atomic_store(rb_dir + (size_t)((kt + 1) & 1) * 8192 + pidx, rv,
                         __ATOMIC_RELAXED, __HIP_MEMORY_SCOPE_AGENT);
    }

    // out stores (retire under the next step's poll)
    const size_t o0 = (size_t)(l15 * 512 + t) * 512 + u;
    const size_t o1 = (size_t)((l15 + 16) * 512 + t) * 512 + u;
    if (dir == 0) {
      outf[o0] = h0;
      outf[o1] = h1;
    } else {
      outb[o0] = (__bf16)h0;
      outb[o1] = (__bf16)h1;
    }

    xA = nxA;
    xB = nxB;
  }
}

// ---------------- final merge ----------------

__global__ void k_add_bwd(float* __restrict__ out, const __bf16* __restrict__ outb) {
  size_t i = ((size_t)blockIdx.x * 256 + threadIdx.x) * 4;
  if (i >= (size_t)32 * 512 * 512) return;
  fvec4 o = *(const fvec4*)(out + i);
  bf16x4 bv = *(const bf16x4*)(outb + i);
#pragma unroll
  for (int j = 0; j < 4; ++j) o[j] += (float)bv[j];
  *(fvec4*)(out + i) = o;
}

// ---------------- host ----------------

extern "C" void kernel_launch(void* const* d_in, const int* in_sizes, int n_in,
                              void* d_out, int out_size, void* d_ws, size_t ws_size,
                              hipStream_t stream) {
  const float* x  = (const float*)d_in[0];
  const float* z  = (const float*)d_in[1];
  const float* Wf = (const float*)d_in[2];
  const float* Uf = (const float*)d_in[3];
  const float* bf = (const float*)d_in[4];
  const float* Wb = (const float*)d_in[5];
  const float* Ub = (const float*)d_in[6];
  const float* bb = (const float*)d_in[7];
  float* out = (float*)d_out;
  char* ws = (char*)d_ws;

  size_t off = 0;
  __bf16* xg = (__bf16*)(ws + off); off += (size_t)16384 * 4096 * 2;   // 134 MB
  __bf16* UT = (__bf16*)(ws + off); off += (size_t)2 * 2048 * 512 * 2; // 4 MB
  unsigned long long* rbuf = (unsigned long long*)(ws + off);
  off += (size_t)2 * 2 * 8192 * 8;                                     // 256 KB
  float* biasp = (float*)(ws + off); off += 4096 * 4;
  char* uni = ws + off;
  __bf16* xb   = (__bf16*)uni;                               // phase 1
  __bf16* WT   = (__bf16*)(uni + (size_t)16384 * 512 * 2);   // phase 1
  __bf16* outb = (__bf16*)uni;                               // phase 2 (aliases xb)

  k_convert_x<<<4096, 256, 0, stream>>>(x, xb);
  k_build_T<<<2048, 256, 0, stream>>>(Wf, bf, WT, biasp);
  k_build_T<<<2048, 256, 0, stream>>>(Wb, bb, WT + (size_t)2048 * 512, biasp + 2048);
  k_build_T<<<2048, 256, 0, stream>>>(Uf, nullptr, UT, nullptr);
  k_build_T<<<2048, 256, 0, stream>>>(Ub, nullptr, UT + (size_t)2048 * 512, nullptr);
  k_init_rec<<<128, 256, 0, stream>>>(z, rbuf);
  k_gemm_xw<<<dim3(32, 128), 256, 0, stream>>>(xb, WT, biasp, xg);
  k_lstm_rec<<<64, 256, 0, stream>>>(xg, z, UT, rbuf, out, outb);
  k_add_bwd<<<8192, 256, 0, stream>>>(out, outb);
}